// Round 5
// baseline (7443.090 us; speedup 1.0000x reference)
//
#include <hip/hip_runtime.h>
#include <hip/hip_fp16.h>
#include <math.h>

#define BATCH 128
#define NDIM 512
#define NPAIR 256          // row-pairs per batch
#define POWER_ITERS 30
#define N_ITERS 500

#define NGRP 8             // 8 groups x 128 threads = 1024-thread block
#define GP 32              // row-pairs per group (NPAIR / NGRP)
// per-thread partition of its 32 owned row-pairs:
#define REGP 16            // pairs in VGPRs (64 VGPRs) -- fits 128-VGPR budget
#define LDSP 2             // pairs in LDS (32 KB/block)
#define STRP 14            // pairs streamed from L2 each matvec (224 KB/block/iter)

typedef _Float16 half2_t __attribute__((ext_vector_type(2)));

union H2x4 { float4 f4; half2_t h[4]; };

// ---------------- helpers ----------------
__device__ __forceinline__ float4 ld4(const float* p) { return *(const float4*)p; }
__device__ __forceinline__ float4 f4_add(float4 a, float4 b) {
  return make_float4(a.x + b.x, a.y + b.y, a.z + b.z, a.w + b.w);
}
__device__ __forceinline__ float wave_sum64(float x) {
#pragma unroll
  for (int off = 1; off < 64; off <<= 1) x += __shfl_xor(x, off, 64);
  return x;
}
__device__ __forceinline__ float wave_max64(float x) {
#pragma unroll
  for (int off = 1; off < 64; off <<= 1) x = fmaxf(x, __shfl_xor(x, off, 64));
  return x;
}

// ---- conversion: Sh[b][pair][col] = half2( sym(2p,col), sym(2p+1,col) ) ----
__global__ void sym_conv_kernel(const float* __restrict__ S, half2_t* __restrict__ Sh) {
  const int bb = blockIdx.x, ti = blockIdx.y, tj = blockIdx.z;
  if (tj < ti) return;
  __shared__ float ta[32][33];
  __shared__ float tb[32][33];
  const float* base = S + (size_t)bb * NDIM * NDIM;
  half2_t* dst = Sh + (size_t)bb * NPAIR * NDIM;
  const int tx = threadIdx.x, ty = threadIdx.y;  // 32 x 8
#pragma unroll
  for (int k = 0; k < 4; k++) {
    int r = ty + 8 * k;
    ta[r][tx] = base[(size_t)(ti * 32 + r) * NDIM + tj * 32 + tx];
    tb[r][tx] = base[(size_t)(tj * 32 + r) * NDIM + ti * 32 + tx];
  }
  __syncthreads();
#pragma unroll
  for (int k = 0; k < 2; k++) {
    int pi = ty + 8 * k;  // local pair 0..15
    float v0 = 0.5f * (ta[2 * pi][tx] + tb[tx][2 * pi]);
    float v1 = 0.5f * (ta[2 * pi + 1][tx] + tb[tx][2 * pi + 1]);
    half2_t o; o[0] = (_Float16)v0; o[1] = (_Float16)v1;
    dst[(size_t)(ti * 16 + pi) * NDIM + tj * 32 + tx] = o;
  }
  if (ti != tj) {
#pragma unroll
    for (int k = 0; k < 2; k++) {
      int pi = ty + 8 * k;
      float v0 = 0.5f * (tb[2 * pi][tx] + ta[tx][2 * pi]);
      float v1 = 0.5f * (tb[2 * pi + 1][tx] + ta[tx][2 * pi + 1]);
      half2_t o; o[0] = (_Float16)v0; o[1] = (_Float16)v1;
      dst[(size_t)(tj * 16 + pi) * NDIM + ti * 32 + tx] = o;
    }
  }
}

// ---- matvec partial over this thread's 32 pairs: regs + LDS + chunked L2 stream ----
__device__ __forceinline__ void fd4(float* ac, const H2x4& u, half2_t yy) {
  ac[0] = __builtin_amdgcn_fdot2(u.h[0], yy, ac[0], false);
  ac[1] = __builtin_amdgcn_fdot2(u.h[1], yy, ac[1], false);
  ac[2] = __builtin_amdgcn_fdot2(u.h[2], yy, ac[2], false);
  ac[3] = __builtin_amdgcn_fdot2(u.h[3], yy, ac[3], false);
}

__device__ __forceinline__ float4 matvec(const float4 (&sregq)[REGP],
                                         const float4* __restrict__ ldsSg,
                                         const half2_t* __restrict__ Sb,
                                         const half2_t* __restrict__ yb,
                                         int g, int c) {
  const half2_t* gp = Sb + (size_t)(GP * g + REGP + LDSP) * NDIM + 4 * c;
  float4 stA[4], stB[4];
#pragma unroll
  for (int p = 0; p < 4; p++) stA[p] = *(const float4*)(gp + (size_t)p * NDIM);

  float a[2][4] = {{0, 0, 0, 0}, {0, 0, 0, 0}};
  // register part: pairs [0, REGP) — overlaps chunk-A L2 latency
#pragma unroll
  for (int ch = 0; ch < REGP / 4; ch++) {
    H2x4 y4; y4.f4 = *(const float4*)(yb + 4 * ch);  // wave-uniform LDS broadcast
    float* ac = a[ch & 1];
#pragma unroll
    for (int q = 0; q < 4; q++) {
      H2x4 u; u.f4 = sregq[4 * ch + q];
      fd4(ac, u, y4.h[q]);
    }
  }
#pragma unroll
  for (int p = 0; p < 4; p++) stB[p] = *(const float4*)(gp + (size_t)(4 + p) * NDIM);

  // LDS part: pairs [REGP, REGP+LDSP)
#pragma unroll
  for (int p = 0; p < LDSP; p++) {
    H2x4 u; u.f4 = ldsSg[p * 128 + c];
    fd4(a[p & 1], u, yb[REGP + p]);
  }
  // consume A(0-3), prefetch A(8-11)
#pragma unroll
  for (int p = 0; p < 4; p++) { H2x4 u; u.f4 = stA[p]; fd4(a[p & 1], u, yb[REGP + LDSP + p]); }
#pragma unroll
  for (int p = 0; p < 4; p++) stA[p] = *(const float4*)(gp + (size_t)(8 + p) * NDIM);
  // consume B(4-7), prefetch B(12-13)
#pragma unroll
  for (int p = 0; p < 4; p++) { H2x4 u; u.f4 = stB[p]; fd4(a[p & 1], u, yb[REGP + LDSP + 4 + p]); }
#pragma unroll
  for (int p = 0; p < 2; p++) stB[p] = *(const float4*)(gp + (size_t)(12 + p) * NDIM);
  // consume A(8-11)
#pragma unroll
  for (int p = 0; p < 4; p++) { H2x4 u; u.f4 = stA[p]; fd4(a[p & 1], u, yb[REGP + LDSP + 8 + p]); }
  // consume B(12-13)
#pragma unroll
  for (int p = 0; p < 2; p++) { H2x4 u; u.f4 = stB[p]; fd4(a[p & 1], u, yb[REGP + LDSP + 12 + p]); }

  return make_float4(a[0][0] + a[1][0], a[0][1] + a[1][1],
                     a[0][2] + a[1][2], a[0][3] + a[1][3]);
}

// combine NGRP group-partials for wave0 lane's 8 columns
__device__ __forceinline__ void combine_z(const float* __restrict__ zsc, int lane, float* z8) {
#pragma unroll
  for (int q = 0; q < 2; q++) {
    float4 zz = ld4(zsc + 8 * lane + 4 * q);
#pragma unroll
    for (int gg = 1; gg < NGRP; gg++)
      zz = f4_add(zz, ld4(zsc + gg * NDIM + 8 * lane + 4 * q));
    z8[4 * q + 0] = zz.x; z8[4 * q + 1] = zz.y;
    z8[4 * q + 2] = zz.z; z8[4 * q + 3] = zz.w;
  }
}

__device__ __forceinline__ void store_y(half2_t* yh2, float* yls, int lane, const float* y8) {
  H2x4 yo;
#pragma unroll
  for (int q = 0; q < 4; q++) {
    half2_t v; v[0] = (_Float16)y8[2 * q]; v[1] = (_Float16)y8[2 * q + 1];
    yo.h[q] = v;
  }
  *(float4*)(yh2 + 4 * lane) = yo.f4;
  *(float4*)(yls + 8 * lane)     = make_float4(y8[0], y8[1], y8[2], y8[3]);
  *(float4*)(yls + 8 * lane + 4) = make_float4(y8[4], y8[5], y8[6], y8[7]);
}

__global__ void __launch_bounds__(1024, 4)
qp_solver_h(const float* __restrict__ mu,
            const half2_t* __restrict__ Sh,
            float* __restrict__ out) {
  __shared__ half2_t yh2[NPAIR];               // 1 KB: y fp16 row-pairs (matvec input)
  __shared__ float zsc[NGRP * NDIM];           // 16 KB: per-group matvec partials
  __shared__ float4 ldsS[NGRP * LDSP * 128];   // 32 KB: LDS-resident S slab
  __shared__ float yls[NDIM];                  // 2 KB: y fp32 (wave0 state)
  __shared__ float wls[NDIM];                  // 2 KB: w fp32 (wave0 state)
  __shared__ float mls[NDIM];                  // 2 KB: mu    (wave0 state)
  __shared__ float sstep;
  __shared__ int stopf;
  const int tid = threadIdx.x;
  const int g = tid >> 7;        // 0..7
  const int c = tid & 127;
  const int b = blockIdx.x;
  const half2_t* Sb = Sh + (size_t)b * NPAIR * NDIM;
  const half2_t* yb = yh2 + GP * g;
  const float4* ldsSg = ldsS + g * LDSP * 128;
  const float invn = 1.0f / (float)NDIM;

  // ---- stage: registers + LDS slab ----
  float4 sregq[REGP];
  {
    const half2_t* rp = Sb + (size_t)(GP * g) * NDIM + 4 * c;
#pragma unroll
    for (int p = 0; p < REGP; p++)
      sregq[p] = *(const float4*)(rp + (size_t)p * NDIM);
#pragma unroll
    for (int p = 0; p < LDSP; p++)
      ldsS[(g * LDSP + p) * 128 + c] = *(const float4*)(rp + (size_t)(REGP + p) * NDIM);
  }
  // opaque pin: no remat / re-load from global inside the loops
#pragma unroll
  for (int p = 0; p < REGP; p++) {
    asm volatile("" : "+v"(sregq[p].x), "+v"(sregq[p].y),
                      "+v"(sregq[p].z), "+v"(sregq[p].w));
  }

  if (tid < NPAIR) { half2_t v; v[0] = (_Float16)invn; v[1] = (_Float16)invn; yh2[tid] = v; }
  if (tid < NDIM) {
    yls[tid] = invn;
    wls[tid] = invn;
    mls[tid] = mu[(size_t)b * NDIM + tid];
  }
  if (tid == 0) stopf = 0;
  __syncthreads();

  // ---- power iteration ----
  for (int it = 0; it < POWER_ITERS; it++) {
    float4 z = matvec(sregq, ldsSg, Sb, yb, g, c);
    *(float4*)(zsc + g * NDIM + 4 * c) = z;
    __syncthreads();
    if (tid < 64) {
      float z8[8];
      combine_z(zsc, tid, z8);
      float ss = 0.f;
#pragma unroll
      for (int k = 0; k < 8; k++) ss += z8[k] * z8[k];
      ss = wave_sum64(ss);
      float inv = 1.0f / (sqrtf(ss) + 1e-12f);
      float y8[8];
#pragma unroll
      for (int k = 0; k < 8; k++) y8[k] = z8[k] * inv;
      store_y(yh2, yls, tid, y8);
    }
    __syncthreads();
  }

  // ---- lambda_max, step ----
  {
    float4 z = matvec(sregq, ldsSg, Sb, yb, g, c);
    *(float4*)(zsc + g * NDIM + 4 * c) = z;
    __syncthreads();
    if (tid < 64) {
      float z8[8];
      combine_z(zsc, tid, z8);
      float dd = 0.f;
#pragma unroll
      for (int k = 0; k < 8; k++) dd += z8[k] * yls[8 * tid + k];
      dd = wave_sum64(dd);
      if (tid == 0) sstep = 1.0f / (2.0f * dd + 1e-8f);
    }
    __syncthreads();
  }
  const float step = sstep;

  // ---- FISTA init ----
  if (tid < NPAIR) { half2_t v; v[0] = (_Float16)invn; v[1] = (_Float16)invn; yh2[tid] = v; }
  if (tid < NDIM) { yls[tid] = invn; wls[tid] = invn; }
  __syncthreads();

  float t = 1.0f;
  int streak = 0;
  for (int it = 0; it < N_ITERS; it++) {
    float4 z = matvec(sregq, ldsSg, Sb, yb, g, c);
    *(float4*)(zsc + g * NDIM + 4 * c) = z;
    __syncthreads();
    if (tid < 64) {
      float z8[8], v8[8], y8[8], mu8[8], w8[8];
      combine_z(zsc, tid, z8);
#pragma unroll
      for (int q = 0; q < 2; q++) {
        float4 yq = ld4(yls + 8 * tid + 4 * q);
        float4 mq = ld4(mls + 8 * tid + 4 * q);
        float4 wq = ld4(wls + 8 * tid + 4 * q);
        y8[4*q+0]=yq.x; y8[4*q+1]=yq.y; y8[4*q+2]=yq.z; y8[4*q+3]=yq.w;
        mu8[4*q+0]=mq.x; mu8[4*q+1]=mq.y; mu8[4*q+2]=mq.z; mu8[4*q+3]=mq.w;
        w8[4*q+0]=wq.x; w8[4*q+1]=wq.y; w8[4*q+2]=wq.z; w8[4*q+3]=wq.w;
      }
#pragma unroll
      for (int k = 0; k < 8; k++)
        v8[k] = y8[k] - step * (2.0f * z8[k] - mu8[k]);

      // Michelot fixed-point simplex projection (exact)
      float th = -1e30f;
      for (int m = 0; m < 64; m++) {
        float s = 0.f, cn = 0.f;
#pragma unroll
        for (int k = 0; k < 8; k++)
          if (v8[k] > th) { s += v8[k]; cn += 1.f; }
#pragma unroll
        for (int off = 1; off < 64; off <<= 1) {
          s  += __shfl_xor(s, off, 64);
          cn += __shfl_xor(cn, off, 64);
        }
        float thn = (s - 1.0f) / cn;
        if (!(thn > th)) break;
        th = thn;
      }

      float tn = 0.5f * (1.0f + sqrtf(1.0f + 4.0f * t * t));
      float coef = (t - 1.0f) / tn;
      float maxinc = 0.f;
      float yn[8];
#pragma unroll
      for (int k = 0; k < 8; k++) {
        float wn = fmaxf(v8[k] - th, 0.0f);
        maxinc = fmaxf(maxinc, fabsf(wn - w8[k]));
        yn[k] = wn + coef * (wn - w8[k]);
        w8[k] = wn;
      }
      t = tn;
      store_y(yh2, yls, tid, yn);
      *(float4*)(wls + 8 * tid)     = make_float4(w8[0], w8[1], w8[2], w8[3]);
      *(float4*)(wls + 8 * tid + 4) = make_float4(w8[4], w8[5], w8[6], w8[7]);
      maxinc = wave_max64(maxinc);
      streak = (maxinc < 1e-7f) ? streak + 1 : 0;
      if (tid == 0 && streak >= 3) stopf = 1;
    }
    __syncthreads();
    if (stopf) break;
  }

  if (tid < NDIM) out[(size_t)b * NDIM + tid] = wls[tid];
}

// ---------------- launch ----------------
extern "C" void kernel_launch(void* const* d_in, const int* in_sizes, int n_in,
                              void* d_out, int out_size, void* d_ws, size_t ws_size,
                              hipStream_t stream) {
  const float* mu = (const float*)d_in[0];
  const float* Sg = (const float*)d_in[1];
  if (n_in >= 2 && in_sizes[0] > in_sizes[1]) { mu = (const float*)d_in[1]; Sg = (const float*)d_in[0]; }
  float* out = (float*)d_out;

  half2_t* Sh = (half2_t*)d_ws;  // 64 MB (ws verified sufficient in round 2)
  sym_conv_kernel<<<dim3(BATCH, 16, 16), dim3(32, 8), 0, stream>>>(Sg, Sh);
  qp_solver_h<<<dim3(BATCH), dim3(1024), 0, stream>>>(mu, Sh, out);
}

// Round 6
// 3643.592 us; speedup vs baseline: 2.0428x; 2.0428x over previous
//
#include <hip/hip_runtime.h>
#include <hip/hip_fp16.h>
#include <math.h>

#define BATCH 128
#define NDIM 512
#define NPAIR 256          // row-pairs per batch
#define HPAIR 128          // row-pairs per block (half batch)
#define NGRP 4             // 4 groups x 128 threads = 512-thread block
#define GPP 32             // pairs per group (HPAIR / NGRP)
#define REGP 26            // pairs per thread in VGPRs (104 VGPRs)
#define LDSP 6             // pairs per thread in LDS (48 KB/block)
#define POWER_ITERS 30
#define N_ITERS 500

#define SLAB_BYTES (NPAIR * NDIM * 4)   // 512 KB per batch (fp16 pairs)
#define HALF_BYTES (SLAB_BYTES / 2)     // 256 KB per block's half
#define XTAIL 8192                      // tail carve: z slots (2x2KB) + flag
#define TAGBASE 0x5EED0000

typedef _Float16 half2_t __attribute__((ext_vector_type(2)));
union H2x4 { float4 f4; half2_t h[4]; };

// ---------------- helpers ----------------
__device__ __forceinline__ float4 ld4(const float* p) { return *(const float4*)p; }
__device__ __forceinline__ float wave_sum64(float x) {
#pragma unroll
  for (int off = 1; off < 64; off <<= 1) x += __shfl_xor(x, off, 64);
  return x;
}
__device__ __forceinline__ float wave_max64(float x) {
#pragma unroll
  for (int off = 1; off < 64; off <<= 1) x = fmaxf(x, __shfl_xor(x, off, 64));
  return x;
}

// ---- conversion: Sh[b][pair][col] = half2( sym(2p,col), sym(2p+1,col) ) ----
__global__ void sym_conv_kernel(const float* __restrict__ S, half2_t* __restrict__ Sh) {
  const int bb = blockIdx.x, ti = blockIdx.y, tj = blockIdx.z;
  if (tj < ti) return;
  __shared__ float ta[32][33];
  __shared__ float tb[32][33];
  const float* base = S + (size_t)bb * NDIM * NDIM;
  half2_t* dst = Sh + (size_t)bb * NPAIR * NDIM;
  const int tx = threadIdx.x, ty = threadIdx.y;  // 32 x 8
#pragma unroll
  for (int k = 0; k < 4; k++) {
    int r = ty + 8 * k;
    ta[r][tx] = base[(size_t)(ti * 32 + r) * NDIM + tj * 32 + tx];
    tb[r][tx] = base[(size_t)(tj * 32 + r) * NDIM + ti * 32 + tx];
  }
  __syncthreads();
#pragma unroll
  for (int k = 0; k < 2; k++) {
    int pi = ty + 8 * k;
    float v0 = 0.5f * (ta[2 * pi][tx] + tb[tx][2 * pi]);
    float v1 = 0.5f * (ta[2 * pi + 1][tx] + tb[tx][2 * pi + 1]);
    half2_t o; o[0] = (_Float16)v0; o[1] = (_Float16)v1;
    dst[(size_t)(ti * 16 + pi) * NDIM + tj * 32 + tx] = o;
  }
  if (ti != tj) {
#pragma unroll
    for (int k = 0; k < 2; k++) {
      int pi = ty + 8 * k;
      float v0 = 0.5f * (tb[2 * pi][tx] + ta[tx][2 * pi]);
      float v1 = 0.5f * (tb[2 * pi + 1][tx] + ta[tx][2 * pi + 1]);
      half2_t o; o[0] = (_Float16)v0; o[1] = (_Float16)v1;
      dst[(size_t)(tj * 16 + pi) * NDIM + ti * 32 + tx] = o;
    }
  }
}

// ---- matvec partial over this thread's 32 pairs (26 regs + 6 LDS, 0 streamed) ----
__device__ __forceinline__ void fd4(float* ac, const H2x4& u, half2_t yy) {
  ac[0] = __builtin_amdgcn_fdot2(u.h[0], yy, ac[0], false);
  ac[1] = __builtin_amdgcn_fdot2(u.h[1], yy, ac[1], false);
  ac[2] = __builtin_amdgcn_fdot2(u.h[2], yy, ac[2], false);
  ac[3] = __builtin_amdgcn_fdot2(u.h[3], yy, ac[3], false);
}

__device__ __forceinline__ float4 matvec(const float4 (&sregq)[REGP],
                                         const float4 (*ldsSg)[128],
                                         const half2_t* __restrict__ yb,
                                         int c) {
  float a[2][4] = {{0, 0, 0, 0}, {0, 0, 0, 0}};
#pragma unroll
  for (int ch = 0; ch < GPP / 4; ch++) {
    H2x4 y4; y4.f4 = *(const float4*)(yb + 4 * ch);  // wave-uniform LDS broadcast
#pragma unroll
    for (int q = 0; q < 4; q++) {
      const int p = 4 * ch + q;  // constant under full unroll -> branch folds
      H2x4 u;
      if (p < REGP) u.f4 = sregq[p];
      else          u.f4 = ldsSg[p - REGP][c];
      fd4(a[p & 1], u, y4.h[q]);
    }
  }
  return make_float4(a[0][0] + a[1][0], a[0][1] + a[1][1],
                     a[0][2] + a[1][2], a[0][3] + a[1][3]);
}

// combine the block's 4 group-partials for wave0 lane's 8 columns
__device__ __forceinline__ void combine_z(const float* __restrict__ zsc, int lane, float* z8) {
#pragma unroll
  for (int q = 0; q < 2; q++) {
    float4 zz = ld4(zsc + 8 * lane + 4 * q);
#pragma unroll
    for (int gg = 1; gg < NGRP; gg++) {
      float4 t = ld4(zsc + gg * NDIM + 8 * lane + 4 * q);
      zz.x += t.x; zz.y += t.y; zz.z += t.z; zz.w += t.w;
    }
    z8[4 * q + 0] = zz.x; z8[4 * q + 1] = zz.y;
    z8[4 * q + 2] = zz.z; z8[4 * q + 3] = zz.w;
  }
}

// paired-block exchange: publish my 512-length partial, read partner's, sum.
// Slots double-buffered by itc parity; exact-match monotonic tags survive junk init.
__device__ __forceinline__ void exchange_z(float* myz, int* myfl,
                                           const float* pz, const int* pfl,
                                           int itc, int L,
                                           const float* zloc8, float* z8) {
  const int slot = itc & 1;
  float* zo = myz + slot * NDIM;
  const float* zi = pz + slot * NDIM;
#pragma unroll
  for (int k = 0; k < 8; k++)
    __hip_atomic_store(zo + 8 * L + k, zloc8[k], __ATOMIC_RELAXED, __HIP_MEMORY_SCOPE_AGENT);
  const int tag = TAGBASE + itc;
  if (L == 0)  // release waits on the whole wave's outstanding stores (vmcnt)
    __hip_atomic_store(myfl, tag, __ATOMIC_RELEASE, __HIP_MEMORY_SCOPE_AGENT);
  int guard = 0;
  while (__hip_atomic_load(pfl, __ATOMIC_ACQUIRE, __HIP_MEMORY_SCOPE_AGENT) != tag) {
    if (++guard > (1 << 24)) break;  // safety valve: never hit when protocol holds
  }
#pragma unroll
  for (int k = 0; k < 8; k++)
    z8[k] = zloc8[k] +
            __hip_atomic_load(zi + 8 * L + k, __ATOMIC_RELAXED, __HIP_MEMORY_SCOPE_AGENT);
}

__global__ void __launch_bounds__(512, 1)  // 1 block/CU floor -> 256-VGPR budget
qp_solver_h(const float* __restrict__ mu, half2_t* Sh, float* __restrict__ out) {
  __shared__ float4 ldsS[NGRP][LDSP][128];  // 48 KB
  __shared__ float zsc[NGRP * NDIM];        // 8 KB
  __shared__ half2_t yh2[HPAIR];            // 512 B: y pairs of MY half
  __shared__ float sstep;
  __shared__ int stopf;

  const int tid = threadIdx.x;
  const int g = tid >> 7, c = tid & 127;
  const int blk = blockIdx.x;
  const int b = blk & (BATCH - 1);
  const int h = blk >> 7;  // 0 or 1: which row-half of batch b
  const half2_t* Sb = Sh + (size_t)b * NPAIR * NDIM;

  char* slab = (char*)Sh + (size_t)b * SLAB_BYTES;
  float* myz = (float*)(slab + (size_t)h * HALF_BYTES + HALF_BYTES - XTAIL);
  int* myfl = (int*)((char*)myz + 2 * NDIM * 4);
  const float* pz = (const float*)(slab + (size_t)(h ^ 1) * HALF_BYTES + HALF_BYTES - XTAIL);
  const int* pfl = (const int*)((char*)pz + 2 * NDIM * 4);

  const float invn = 1.0f / (float)NDIM;

  // ---- stage my half of S: 26 pairs -> VGPRs, 6 pairs -> LDS (before any tail clobber) ----
  float4 sregq[REGP];
  {
    const half2_t* rp = Sb + (size_t)(HPAIR * h + GPP * g) * NDIM + 4 * c;
#pragma unroll
    for (int p = 0; p < REGP; p++) sregq[p] = *(const float4*)(rp + (size_t)p * NDIM);
#pragma unroll
    for (int p = 0; p < LDSP; p++) ldsS[g][p][c] = *(const float4*)(rp + (size_t)(REGP + p) * NDIM);
  }
#pragma unroll
  for (int p = 0; p < REGP; p++)
    asm volatile("" : "+v"(sregq[p].x), "+v"(sregq[p].y), "+v"(sregq[p].z), "+v"(sregq[p].w));

  if (tid < HPAIR) { half2_t v; v[0] = (_Float16)invn; v[1] = (_Float16)invn; yh2[tid] = v; }
  if (tid == 0) stopf = 0;
  __syncthreads();

  const half2_t* yb = yh2 + GPP * g;
  float y8[8], w8[8], mu8[8];  // wave0 state (full 512-vector, 8/lane)
  int itc = 0;                 // exchange counter: tags + slot parity

  // ---- power iteration (30) ----
  for (int it = 0; it < POWER_ITERS; it++) {
    float4 z = matvec(sregq, ldsS[g], yb, c);
    *(float4*)(zsc + g * NDIM + 4 * c) = z;
    __syncthreads();
    if (tid < 64) {
      float zloc8[8], z8[8];
      combine_z(zsc, tid, zloc8);
      exchange_z(myz, myfl, pz, pfl, itc, tid, zloc8, z8);
      float ss = 0.f;
#pragma unroll
      for (int k = 0; k < 8; k++) ss += z8[k] * z8[k];
      ss = wave_sum64(ss);
      float inv = 1.0f / (sqrtf(ss) + 1e-12f);
#pragma unroll
      for (int k = 0; k < 8; k++) y8[k] = z8[k] * inv;
      if ((tid >> 5) == h) {  // my half's pairs -> LDS for next matvec
        H2x4 yo;
#pragma unroll
        for (int q = 0; q < 4; q++) {
          half2_t v; v[0] = (_Float16)y8[2 * q]; v[1] = (_Float16)y8[2 * q + 1];
          yo.h[q] = v;
        }
        *(float4*)(yh2 + 4 * (tid & 31)) = yo.f4;
      }
    }
    itc++;
    __syncthreads();
  }

  // ---- lambda_max, step ----
  {
    float4 z = matvec(sregq, ldsS[g], yb, c);
    *(float4*)(zsc + g * NDIM + 4 * c) = z;
    __syncthreads();
    if (tid < 64) {
      float zloc8[8], z8[8];
      combine_z(zsc, tid, zloc8);
      exchange_z(myz, myfl, pz, pfl, itc, tid, zloc8, z8);
      float dd = 0.f;
#pragma unroll
      for (int k = 0; k < 8; k++) dd += z8[k] * y8[k];
      dd = wave_sum64(dd);
      if (tid == 0) sstep = 1.0f / (2.0f * dd + 1e-8f);
    }
    itc++;
    __syncthreads();
  }
  const float step = sstep;

  // ---- FISTA init ----
  if (tid < 64) {
#pragma unroll
    for (int k = 0; k < 8; k++) { w8[k] = invn; y8[k] = invn; }
    float4 m0 = ld4(mu + (size_t)b * NDIM + 8 * tid);
    float4 m1 = ld4(mu + (size_t)b * NDIM + 8 * tid + 4);
    mu8[0] = m0.x; mu8[1] = m0.y; mu8[2] = m0.z; mu8[3] = m0.w;
    mu8[4] = m1.x; mu8[5] = m1.y; mu8[6] = m1.z; mu8[7] = m1.w;
  }
  if (tid < HPAIR) { half2_t v; v[0] = (_Float16)invn; v[1] = (_Float16)invn; yh2[tid] = v; }
  __syncthreads();

  float t = 1.0f;
  int streak = 0;
  for (int it = 0; it < N_ITERS; it++) {
    float4 z = matvec(sregq, ldsS[g], yb, c);
    *(float4*)(zsc + g * NDIM + 4 * c) = z;
    __syncthreads();
    if (tid < 64) {
      float zloc8[8], z8[8], v8[8];
      combine_z(zsc, tid, zloc8);
      exchange_z(myz, myfl, pz, pfl, itc, tid, zloc8, z8);
#pragma unroll
      for (int k = 0; k < 8; k++)
        v8[k] = y8[k] - step * (2.0f * z8[k] - mu8[k]);

      // Michelot fixed-point simplex projection (exact; identical on both blocks)
      float th = -1e30f;
      for (int m = 0; m < 64; m++) {
        float s = 0.f, cn = 0.f;
#pragma unroll
        for (int k = 0; k < 8; k++)
          if (v8[k] > th) { s += v8[k]; cn += 1.f; }
#pragma unroll
        for (int off = 1; off < 64; off <<= 1) {
          s  += __shfl_xor(s, off, 64);
          cn += __shfl_xor(cn, off, 64);
        }
        float thn = (s - 1.0f) / cn;
        if (!(thn > th)) break;
        th = thn;
      }

      float tn = 0.5f * (1.0f + sqrtf(1.0f + 4.0f * t * t));
      float coef = (t - 1.0f) / tn;
      float maxinc = 0.f;
#pragma unroll
      for (int k = 0; k < 8; k++) {
        float wn = fmaxf(v8[k] - th, 0.0f);
        maxinc = fmaxf(maxinc, fabsf(wn - w8[k]));
        y8[k] = wn + coef * (wn - w8[k]);
        w8[k] = wn;
      }
      t = tn;
      if ((tid >> 5) == h) {
        H2x4 yo;
#pragma unroll
        for (int q = 0; q < 4; q++) {
          half2_t v; v[0] = (_Float16)y8[2 * q]; v[1] = (_Float16)y8[2 * q + 1];
          yo.h[q] = v;
        }
        *(float4*)(yh2 + 4 * (tid & 31)) = yo.f4;
      }
      maxinc = wave_max64(maxinc);
      streak = (maxinc < 1e-7f) ? streak + 1 : 0;
      if (tid == 0 && streak >= 3) stopf = 1;
    }
    itc++;
    __syncthreads();
    if (stopf) break;
  }

  // write my half of w (both blocks hold identical full w)
  if (tid < 64 && (tid >> 5) == h) {
    *(float4*)(out + (size_t)b * NDIM + 8 * tid)     = make_float4(w8[0], w8[1], w8[2], w8[3]);
    *(float4*)(out + (size_t)b * NDIM + 8 * tid + 4) = make_float4(w8[4], w8[5], w8[6], w8[7]);
  }
}

// ---------------- launch ----------------
extern "C" void kernel_launch(void* const* d_in, const int* in_sizes, int n_in,
                              void* d_out, int out_size, void* d_ws, size_t ws_size,
                              hipStream_t stream) {
  const float* mu = (const float*)d_in[0];
  const float* Sg = (const float*)d_in[1];
  if (n_in >= 2 && in_sizes[0] > in_sizes[1]) { mu = (const float*)d_in[1]; Sg = (const float*)d_in[0]; }
  float* out = (float*)d_out;

  half2_t* Sh = (half2_t*)d_ws;  // 64 MB (ws >= 64 MB verified in round 2)
  sym_conv_kernel<<<dim3(BATCH, 16, 16), dim3(32, 8), 0, stream>>>(Sg, Sh);
  qp_solver_h<<<dim3(2 * BATCH), dim3(512), 0, stream>>>(mu, Sh, out);
}